// Round 1
// baseline (1594.952 us; speedup 1.0000x reference)
//
#include <hip/hip_runtime.h>

#define NN 100000
#define NE 1600000
#define HID 64
#define EPSV 1e-5f

// ---------- small scratch layout (float indices into ws) ----------
#define SM_SUMS(l)  ((l)*128)
#define SM_SUMSQ(l) ((l)*128 + 64)
#define SM_HS       512
#define SM_C        576
#define SM_QS       640          // 128 floats
#define SM_RACC(s)  (768 + (s)*64)
#define SM_Z(s)     (960 + (s))
#define SM_MAXE(s)  (964 + (s))  // used as unsigned
#define SM_COUNT    1024

// big buffers (float offsets)
#define NPAD        100352L
#define OFF_DINV    1024L
#define OFF_E       (OFF_DINV + NPAD)
#define OFF_H       (OFF_E + NPAD)
#define OFF_Y       (OFF_H + 6400000L)
#define OFF_ACC     (OFF_Y + 6400000L)

// order-preserving float<->uint for atomicMax
static __device__ __forceinline__ unsigned encf(float f) {
  unsigned u = __float_as_uint(f);
  return (u & 0x80000000u) ? ~u : (u | 0x80000000u);
}
static __device__ __forceinline__ float decf(unsigned u) {
  return __uint_as_float((u & 0x80000000u) ? (u ^ 0x80000000u) : ~u);
}

// GraphNorm affine from accumulated sums: gn(x) = sc*x + sh  (per feature j)
static __device__ __forceinline__ void gn_affine(int j, const float* w, const float* b,
                                                 const float* ms, const float* sums,
                                                 const float* sumsq, float& sc, float& sh) {
  const float invn = 1.0f / (float)NN;
  float mean = sums[j] * invn;
  float ex2  = sumsq[j] * invn;
  float m    = ms[j];
  float var  = ex2 - m * mean * mean * (2.0f - m);
  sc = w[j] * rsqrtf(var + EPSV);
  sh = b[j] - sc * m * mean;
}

// ---------------- degree / dinv ----------------
__global__ __launch_bounds__(256) void k_deg(const int* __restrict__ dst, float* __restrict__ deg) {
  int stride = gridDim.x * blockDim.x;
  for (int i = blockIdx.x * blockDim.x + threadIdx.x; i < NE; i += stride)
    atomicAdd(&deg[dst[i]], 1.0f);
}
__global__ __launch_bounds__(256) void k_dinv(float* __restrict__ deg) {
  int stride = gridDim.x * blockDim.x;
  for (int i = blockIdx.x * blockDim.x + threadIdx.x; i < NN; i += stride)
    deg[i] = rsqrtf(deg[i] + 1.0f);
}

// ---------------- gn0 sums over x (D=4) ----------------
__global__ __launch_bounds__(256) void k_sums4(const float* __restrict__ x,
                                               float* __restrict__ sums, float* __restrict__ sumsq) {
  __shared__ float ls[256], lq[256];
  int t = threadIdx.x;
  float s = 0.f, q = 0.f;
  int stride = gridDim.x * blockDim.x;
  for (int idx = blockIdx.x * blockDim.x + t; idx < NN * 4; idx += stride) {
    float v = x[idx];
    s += v; q += v * v;
  }
  ls[t] = s; lq[t] = q;
  __syncthreads();
  if (t < 4) {
    float S = 0.f, Q = 0.f;
    for (int g = t; g < 256; g += 4) { S += ls[g]; Q += lq[g]; }
    atomicAdd(&sums[t], S);
    atomicAdd(&sumsq[t], Q);
  }
}

// ---------------- fused GraphNorm-apply + matmul + dinv prescale ----------------
// y[i,:] = dinv[i] * (gn(h)[i,:] @ W);  acc[i,:] = y[i,:]  (self-loop init)
template <int D>
__global__ __launch_bounds__(256) void k_mm(const float* __restrict__ hin, const float* __restrict__ W,
                                            const float* __restrict__ gw, const float* __restrict__ gb,
                                            const float* __restrict__ gms,
                                            const float* __restrict__ sums, const float* __restrict__ sumsq,
                                            const float* __restrict__ dinv,
                                            float* __restrict__ y, float* __restrict__ acc) {
  __shared__ float Ws[D][64];
  __shared__ float woff[64];
  __shared__ float scale[D], shift[D];
  __shared__ float hl[4][D];
  int t = threadIdx.x;
  if (t < D) {
    float sc, sh;
    gn_affine(t, gw, gb, gms, sums, sumsq, sc, sh);
    scale[t] = sc; shift[t] = sh;
  }
  __syncthreads();
  for (int idx = t; idx < D * 64; idx += 256) {
    int k = idx >> 6;
    Ws[k][idx & 63] = scale[k] * W[idx];
  }
  __syncthreads();
  if (t < 64) {
    float o = 0.f;
#pragma unroll
    for (int k = 0; k < D; ++k) o += shift[k] * W[k * 64 + t];
    woff[t] = o;
  }
  __syncthreads();

  int g = t >> 6, j = t & 63;
  const int nRG = NN / 4;  // 25000, exact
  for (int rg = blockIdx.x; rg < nRG; rg += gridDim.x) {
    int row = rg * 4 + g;
    if (D == 64) hl[g][j] = hin[row * 64 + j];
    else if (j < D) hl[g][j] = hin[row * D + j];
    __syncthreads();
    float a = woff[j];
#pragma unroll 16
    for (int k = 0; k < D; ++k) a += hl[g][k] * Ws[k][j];
    float v = dinv[row] * a;
    y[row * 64 + j] = v;
    acc[row * 64 + j] = v;
    __syncthreads();
  }
}

// ---------------- edge scatter: acc[dst,:] += y[src,:] ----------------
__global__ __launch_bounds__(256) void k_scatter(const int* __restrict__ src, const int* __restrict__ dst,
                                                 const float* __restrict__ y, float* __restrict__ acc) {
  int lane = threadIdx.x & 63;
  int w = threadIdx.x >> 6;
  long wgid = (long)blockIdx.x * 4 + w;
  long nwaves = (long)gridDim.x * 4;
  for (long base = wgid * 64; base < NE; base += nwaves * 64) {
    int e = (int)base + lane;          // NE % 64 == 0, no tail
    int sv = src[e];
    int dv = dst[e];
#pragma unroll 8
    for (int it = 0; it < 64; ++it) {
      int se = __shfl(sv, it, 64);
      int de = __shfl(dv, it, 64);
      float v = y[se * 64 + lane];
      atomicAdd(&acc[de * 64 + lane], v);
    }
  }
}

// ---------------- finalize: h = prelu(dinv*acc + b), accumulate next-gn sums ----------------
__global__ __launch_bounds__(256) void k_fin(const float* __restrict__ acc, const float* __restrict__ dinv,
                                             const float* __restrict__ b, const float* __restrict__ a,
                                             float* __restrict__ h,
                                             float* __restrict__ sums, float* __restrict__ sumsq) {
  __shared__ float ls[256], lq[256];
  int t = threadIdx.x, j = t & 63;
  float bj = b[j];
  bool pr = (a != nullptr);
  float aj = pr ? a[j] : 1.0f;
  float s = 0.f, q = 0.f;
  int stride = gridDim.x * 256;
  for (int idx = blockIdx.x * 256 + t; idx < NN * 64; idx += stride) {
    int i = idx >> 6;
    float v = dinv[i] * acc[idx] + bj;
    if (pr && v < 0.f) v *= aj;
    h[idx] = v;
    s += v; q += v * v;
  }
  ls[t] = s; lq[t] = q;
  __syncthreads();
  if (t < 64) {
    float S = ls[t] + ls[t + 64] + ls[t + 128] + ls[t + 192];
    float Q = lq[t] + lq[t + 64] + lq[t + 128] + lq[t + 192];
    atomicAdd(&sums[j], S);
    atomicAdd(&sumsq[j], Q);
  }
}

// ---------------- Set2Set: LSTM cell (1 block, 256 threads) ----------------
__global__ __launch_bounds__(256) void k_lstm(const float* __restrict__ Wih, const float* __restrict__ Whh,
                                              const float* __restrict__ bih, const float* __restrict__ bhh,
                                              float* __restrict__ sm) {
  __shared__ float qs[128], hsl[64], gates[256];
  int t = threadIdx.x;
  if (t < 128) qs[t] = sm[SM_QS + t];
  if (t < 64) hsl[t] = sm[SM_HS + t];
  __syncthreads();
  float g = bih[t] + bhh[t];
#pragma unroll 16
  for (int k = 0; k < 128; ++k) g += qs[k] * Wih[t * 128 + k];
#pragma unroll 16
  for (int k = 0; k < 64; ++k) g += hsl[k] * Whh[t * 64 + k];
  gates[t] = g;
  __syncthreads();
  if (t < 64) {
    float ig = 1.f / (1.f + expf(-gates[t]));
    float fg = 1.f / (1.f + expf(-gates[64 + t]));
    float gg = tanhf(gates[128 + t]);
    float og = 1.f / (1.f + expf(-gates[192 + t]));
    float c = fg * sm[SM_C + t] + ig * gg;
    float hsn = og * tanhf(c);
    sm[SM_C + t] = c;
    sm[SM_HS + t] = hsn;
  }
}

// ---------------- attention logits e[i] = gn3(h)[i] . hs, track max ----------------
__global__ __launch_bounds__(256) void k_e(const float* __restrict__ h, const float* __restrict__ sm,
                                           const float* __restrict__ gw, const float* __restrict__ gb,
                                           const float* __restrict__ gms,
                                           const float* __restrict__ sums, const float* __restrict__ sumsq,
                                           float* __restrict__ e, unsigned* __restrict__ maxe) {
  __shared__ float hv[64], tmp[64], eoffs;
  __shared__ float wmax[4];
  int t = threadIdx.x;
  if (t < 64) {
    float sc, sh;
    gn_affine(t, gw, gb, gms, sums, sumsq, sc, sh);
    float hs = sm[SM_HS + t];
    hv[t] = sc * hs;
    tmp[t] = sh * hs;
  }
  __syncthreads();
  if (t == 0) {
    float s = 0.f;
    for (int k = 0; k < 64; ++k) s += tmp[k];
    eoffs = s;
  }
  __syncthreads();
  int lane = t & 63, w = t >> 6;
  float hvl = hv[lane];
  float eoff = eoffs;
  float lmax = -3.4e38f;
  long nwaves = (long)gridDim.x * 4;
  for (long i = (long)blockIdx.x * 4 + w; i < NN; i += nwaves) {
    float v = h[i * 64 + lane] * hvl;
#pragma unroll
    for (int off = 32; off; off >>= 1) v += __shfl_xor(v, off, 64);
    float ei = v + eoff;
    if (lane == 0) e[i] = ei;
    lmax = fmaxf(lmax, ei);
  }
  if (lane == 0) wmax[w] = lmax;
  __syncthreads();
  if (t == 0) {
    float m = fmaxf(fmaxf(wmax[0], wmax[1]), fmaxf(wmax[2], wmax[3]));
    atomicMax(maxe, encf(m));
  }
}

// ---------------- softmax accumulate: racc[j] += sum_i p_i h[i,j], Z += sum_i p_i ----------------
__global__ __launch_bounds__(256) void k_soft(const float* __restrict__ h, const float* __restrict__ e,
                                              const unsigned* __restrict__ maxe,
                                              float* __restrict__ racc, float* __restrict__ Z) {
  __shared__ float lr[4][64];
  __shared__ float lz[4];
  int t = threadIdx.x, lane = t & 63, w = t >> 6;
  float mx = decf(*maxe);
  float r = 0.f, z = 0.f;
  long nwaves = (long)gridDim.x * 4;
  for (long i = (long)blockIdx.x * 4 + w; i < NN; i += nwaves) {
    float p = expf(e[i] - mx);
    r += p * h[i * 64 + lane];
    z += p;
  }
  lr[w][lane] = r;
  if (lane == 0) lz[w] = z;
  __syncthreads();
  if (t < 64) {
    float R = lr[0][t] + lr[1][t] + lr[2][t] + lr[3][t];
    atomicAdd(&racc[t], R);
  }
  if (t == 0) atomicAdd(Z, lz[0] + lz[1] + lz[2] + lz[3]);
}

// ---------------- q_star update (+ final output write) ----------------
__global__ __launch_bounds__(64) void k_qstar(const float* __restrict__ racc, const float* __restrict__ Z,
                                              const float* __restrict__ gw, const float* __restrict__ gb,
                                              const float* __restrict__ gms,
                                              const float* __restrict__ sums, const float* __restrict__ sumsq,
                                              float* __restrict__ sm, float* __restrict__ out) {
  int t = threadIdx.x;
  if (t < 64) {
    float sc, sh;
    gn_affine(t, gw, gb, gms, sums, sumsq, sc, sh);
    float r = sc * racc[t] / Z[0] + sh;
    float hs = sm[SM_HS + t];
    sm[SM_QS + t] = hs;
    sm[SM_QS + 64 + t] = r;
    if (out) { out[t] = hs; out[64 + t] = r; }
  }
}

extern "C" void kernel_launch(void* const* d_in, const int* in_sizes, int n_in,
                              void* d_out, int out_size, void* d_ws, size_t ws_size,
                              hipStream_t stream) {
  const float* x     = (const float*)d_in[0];
  const float* gn0_w = (const float*)d_in[1];
  const float* gn0_b = (const float*)d_in[2];
  const float* gn0_ms= (const float*)d_in[3];
  const float* W1    = (const float*)d_in[4];
  const float* b1    = (const float*)d_in[5];
  const float* a1    = (const float*)d_in[6];
  const float* gn1_w = (const float*)d_in[7];
  const float* gn1_b = (const float*)d_in[8];
  const float* gn1_ms= (const float*)d_in[9];
  const float* W2    = (const float*)d_in[10];
  const float* b2    = (const float*)d_in[11];
  const float* a2    = (const float*)d_in[12];
  const float* gn2_w = (const float*)d_in[13];
  const float* gn2_b = (const float*)d_in[14];
  const float* gn2_ms= (const float*)d_in[15];
  const float* W3    = (const float*)d_in[16];
  const float* b3    = (const float*)d_in[17];
  const float* gn3_w = (const float*)d_in[18];
  const float* gn3_b = (const float*)d_in[19];
  const float* gn3_ms= (const float*)d_in[20];
  const float* Wih   = (const float*)d_in[21];
  const float* Whh   = (const float*)d_in[22];
  const float* bih   = (const float*)d_in[23];
  const float* bhh   = (const float*)d_in[24];
  const int*   eidx  = (const int*)d_in[25];
  const int* esrc = eidx;
  const int* edst = eidx + NE;

  float* sm   = (float*)d_ws;
  float* dinv = sm + OFF_DINV;
  float* ebuf = sm + OFF_E;
  float* h    = sm + OFF_H;
  float* y    = sm + OFF_Y;
  float* acc  = sm + OFF_ACC;
  float* out  = (float*)d_out;

  // zero small accumulators + deg
  hipMemsetAsync(sm, 0, SM_COUNT * sizeof(float), stream);
  hipMemsetAsync(dinv, 0, NN * sizeof(float), stream);

  k_deg<<<2048, 256, 0, stream>>>(edst, dinv);
  k_dinv<<<512, 256, 0, stream>>>(dinv);
  k_sums4<<<1024, 256, 0, stream>>>(x, sm + SM_SUMS(0), sm + SM_SUMSQ(0));

  // layer 1
  k_mm<4><<<2048, 256, 0, stream>>>(x, W1, gn0_w, gn0_b, gn0_ms,
                                    sm + SM_SUMS(0), sm + SM_SUMSQ(0), dinv, y, acc);
  k_scatter<<<6250, 256, 0, stream>>>(esrc, edst, y, acc);
  k_fin<<<2048, 256, 0, stream>>>(acc, dinv, b1, a1, h, sm + SM_SUMS(1), sm + SM_SUMSQ(1));

  // layer 2
  k_mm<64><<<2048, 256, 0, stream>>>(h, W2, gn1_w, gn1_b, gn1_ms,
                                     sm + SM_SUMS(1), sm + SM_SUMSQ(1), dinv, y, acc);
  k_scatter<<<6250, 256, 0, stream>>>(esrc, edst, y, acc);
  k_fin<<<2048, 256, 0, stream>>>(acc, dinv, b2, a2, h, sm + SM_SUMS(2), sm + SM_SUMSQ(2));

  // layer 3 (no prelu)
  k_mm<64><<<2048, 256, 0, stream>>>(h, W3, gn2_w, gn2_b, gn2_ms,
                                     sm + SM_SUMS(2), sm + SM_SUMSQ(2), dinv, y, acc);
  k_scatter<<<6250, 256, 0, stream>>>(esrc, edst, y, acc);
  k_fin<<<2048, 256, 0, stream>>>(acc, dinv, b3, nullptr, h, sm + SM_SUMS(3), sm + SM_SUMSQ(3));

  // Set2Set, 3 steps
  for (int s = 0; s < 3; ++s) {
    k_lstm<<<1, 256, 0, stream>>>(Wih, Whh, bih, bhh, sm);
    k_e<<<1024, 256, 0, stream>>>(h, sm, gn3_w, gn3_b, gn3_ms,
                                  sm + SM_SUMS(3), sm + SM_SUMSQ(3),
                                  ebuf, (unsigned*)(sm + SM_MAXE(s)));
    k_soft<<<1024, 256, 0, stream>>>(h, ebuf, (const unsigned*)(sm + SM_MAXE(s)),
                                     sm + SM_RACC(s), sm + SM_Z(s));
    k_qstar<<<1, 64, 0, stream>>>(sm + SM_RACC(s), sm + SM_Z(s),
                                  gn3_w, gn3_b, gn3_ms,
                                  sm + SM_SUMS(3), sm + SM_SUMSQ(3),
                                  sm, (s == 2) ? out : nullptr);
  }
}

// Round 2
// 903.857 us; speedup vs baseline: 1.7646x; 1.7646x over previous
//
#include <hip/hip_runtime.h>

#define NN 100000
#define NE 1600000
#define HID 64
#define EPSV 1e-5f

// ---------- small scratch layout (float indices into ws) ----------
#define SM_SUMS(l)  ((l)*128)
#define SM_SUMSQ(l) ((l)*128 + 64)
#define SM_HS       512
#define SM_C        576
#define SM_QS       640          // 128 floats
#define SM_RACC(s)  (768 + (s)*64)
#define SM_Z(s)     (960 + (s))
#define SM_MAXE(s)  (964 + (s))  // used as unsigned
#define SM_COUNT    1024

// big buffers (float offsets)
#define NPAD        100352L
#define OFF_DINV    1024L
#define OFF_E       (OFF_DINV + NPAD)
#define OFF_H       (OFF_E + NPAD)
#define OFF_Y       (OFF_H + 6400000L)
#define OFF_INT     (OFF_Y + 6400000L)
#define NSCAN1      391          // ceil(100000/256)

// order-preserving float<->uint for atomicMax
static __device__ __forceinline__ unsigned encf(float f) {
  unsigned u = __float_as_uint(f);
  return (u & 0x80000000u) ? ~u : (u | 0x80000000u);
}
static __device__ __forceinline__ float decf(unsigned u) {
  return __uint_as_float((u & 0x80000000u) ? (u ^ 0x80000000u) : ~u);
}

// GraphNorm affine from accumulated sums: gn(x) = sc*x + sh  (per feature j)
static __device__ __forceinline__ void gn_affine(int j, const float* w, const float* b,
                                                 const float* ms, const float* sums,
                                                 const float* sumsq, float& sc, float& sh) {
  const float invn = 1.0f / (float)NN;
  float mean = sums[j] * invn;
  float ex2  = sumsq[j] * invn;
  float m    = ms[j];
  float var  = ex2 - m * mean * mean * (2.0f - m);
  sc = w[j] * rsqrtf(var + EPSV);
  sh = b[j] - sc * m * mean;
}

// ---------------- in-degree histogram (int) ----------------
__global__ __launch_bounds__(256) void k_deg(const int* __restrict__ dst, int* __restrict__ degi) {
  int stride = gridDim.x * blockDim.x;
  for (int i = blockIdx.x * blockDim.x + threadIdx.x; i < NE; i += stride)
    atomicAdd(&degi[dst[i]], 1);
}

// ---------------- 3-kernel exclusive scan over degi -> rowptr ----------------
__global__ __launch_bounds__(256) void k_scan1(const int* __restrict__ degi,
                                               int* __restrict__ excl, int* __restrict__ bsum) {
  __shared__ int ws[4];
  int t = threadIdx.x, lane = t & 63;
  int gid = blockIdx.x * 256 + t;
  int v = (gid < NN) ? degi[gid] : 0;
  int incl = v;
#pragma unroll
  for (int off = 1; off < 64; off <<= 1) {
    int u = __shfl_up(incl, off, 64);
    if (lane >= off) incl += u;
  }
  if (lane == 63) ws[t >> 6] = incl;
  __syncthreads();
  if (t == 0) {
    int s = 0;
#pragma unroll
    for (int w = 0; w < 4; ++w) { int tv = ws[w]; ws[w] = s; s += tv; }
    bsum[blockIdx.x] = s;
  }
  __syncthreads();
  if (gid < NN) excl[gid] = incl - v + ws[t >> 6];
}

__global__ __launch_bounds__(512) void k_scan2(int* __restrict__ bsum) {
  __shared__ int ws[8];
  int t = threadIdx.x, lane = t & 63;
  int v = (t < NSCAN1) ? bsum[t] : 0;
  int incl = v;
#pragma unroll
  for (int off = 1; off < 64; off <<= 1) {
    int u = __shfl_up(incl, off, 64);
    if (lane >= off) incl += u;
  }
  if (lane == 63) ws[t >> 6] = incl;
  __syncthreads();
  if (t == 0) {
    int s = 0;
#pragma unroll
    for (int w = 0; w < 8; ++w) { int tv = ws[w]; ws[w] = s; s += tv; }
  }
  __syncthreads();
  if (t < NSCAN1) bsum[t] = incl - v + ws[t >> 6];
}

// rowptr += block offset; init cursor; compute dinv
__global__ __launch_bounds__(256) void k_scan3(int* __restrict__ rowptr, const int* __restrict__ bsum,
                                               const int* __restrict__ degi,
                                               int* __restrict__ cursor, float* __restrict__ dinv) {
  int t = threadIdx.x;
  int gid = blockIdx.x * 256 + t;
  if (gid < NN) {
    int r = rowptr[gid] + bsum[blockIdx.x];
    rowptr[gid] = r;
    cursor[gid] = r;
    dinv[gid] = rsqrtf((float)degi[gid] + 1.0f);
  }
  if (gid == 0) rowptr[NN] = NE;
}

// ---------------- CSR fill: col[pos] = src, grouped by dst ----------------
__global__ __launch_bounds__(256) void k_fill(const int* __restrict__ src, const int* __restrict__ dst,
                                              int* __restrict__ cursor, int* __restrict__ col) {
  int stride = gridDim.x * blockDim.x;
  for (int e = blockIdx.x * blockDim.x + threadIdx.x; e < NE; e += stride) {
    int d = dst[e];
    int pos = atomicAdd(&cursor[d], 1);
    col[pos] = src[e];
  }
}

// ---------------- gn0 sums over x (D=4) ----------------
__global__ __launch_bounds__(256) void k_sums4(const float* __restrict__ x,
                                               float* __restrict__ sums, float* __restrict__ sumsq) {
  __shared__ float ls[256], lq[256];
  int t = threadIdx.x;
  float s = 0.f, q = 0.f;
  int stride = gridDim.x * blockDim.x;
  for (int idx = blockIdx.x * blockDim.x + t; idx < NN * 4; idx += stride) {
    float v = x[idx];
    s += v; q += v * v;
  }
  ls[t] = s; lq[t] = q;
  __syncthreads();
  if (t < 4) {
    float S = 0.f, Q = 0.f;
    for (int g = t; g < 256; g += 4) { S += ls[g]; Q += lq[g]; }
    atomicAdd(&sums[t], S);
    atomicAdd(&sumsq[t], Q);
  }
}

// ---------------- fused GraphNorm-apply + matmul + dinv prescale ----------------
// y[i,:] = dinv[i] * (gn(h)[i,:] @ W)
template <int D>
__global__ __launch_bounds__(256) void k_mm(const float* __restrict__ hin, const float* __restrict__ W,
                                            const float* __restrict__ gw, const float* __restrict__ gb,
                                            const float* __restrict__ gms,
                                            const float* __restrict__ sums, const float* __restrict__ sumsq,
                                            const float* __restrict__ dinv,
                                            float* __restrict__ y) {
  __shared__ float Ws[D][64];
  __shared__ float woff[64];
  __shared__ float scale[D], shift[D];
  __shared__ float hl[4][D];
  int t = threadIdx.x;
  if (t < D) {
    float sc, sh;
    gn_affine(t, gw, gb, gms, sums, sumsq, sc, sh);
    scale[t] = sc; shift[t] = sh;
  }
  __syncthreads();
  for (int idx = t; idx < D * 64; idx += 256) {
    int k = idx >> 6;
    Ws[k][idx & 63] = scale[k] * W[idx];
  }
  __syncthreads();
  if (t < 64) {
    float o = 0.f;
#pragma unroll
    for (int k = 0; k < D; ++k) o += shift[k] * W[k * 64 + t];
    woff[t] = o;
  }
  __syncthreads();

  int g = t >> 6, j = t & 63;
  const int nRG = NN / 4;  // 25000, exact
  for (int rg = blockIdx.x; rg < nRG; rg += gridDim.x) {
    int row = rg * 4 + g;
    if (D == 64) hl[g][j] = hin[row * 64 + j];
    else if (j < D) hl[g][j] = hin[row * D + j];
    __syncthreads();
    float a = woff[j];
#pragma unroll 16
    for (int k = 0; k < D; ++k) a += hl[g][k] * Ws[k][j];
    y[row * 64 + j] = dinv[row] * a;
    __syncthreads();
  }
}

// ---------------- fused CSR gather + finalize: h = prelu(dinv*(y_self + sum_in y) + b) ----------------
__global__ __launch_bounds__(256) void k_gather_fin(const float* __restrict__ y,
                                                    const int* __restrict__ rowptr, const int* __restrict__ col,
                                                    const float* __restrict__ dinv,
                                                    const float* __restrict__ b, const float* __restrict__ a,
                                                    float* __restrict__ h,
                                                    float* __restrict__ sums, float* __restrict__ sumsq) {
  __shared__ float ls[256], lq[256];
  int t = threadIdx.x, lane = t & 63, w = t >> 6;
  float bj = b[lane];
  bool pr = (a != nullptr);
  float aj = pr ? a[lane] : 1.0f;
  float s = 0.f, q = 0.f;
  int nwaves = gridDim.x * 4;
  for (int i = blockIdx.x * 4 + w; i < NN; i += nwaves) {
    float v = y[i * 64 + lane];   // self-loop (dinv-prescaled)
    int p0 = rowptr[i], p1 = rowptr[i + 1];
    int p = p0;
    for (; p + 2 <= p1; p += 2) {
      int s0 = col[p], s1 = col[p + 1];
      float v0 = y[s0 * 64 + lane];
      float v1 = y[s1 * 64 + lane];
      v += v0; v += v1;
    }
    if (p < p1) v += y[col[p] * 64 + lane];
    v = dinv[i] * v + bj;
    if (pr && v < 0.f) v *= aj;
    h[i * 64 + lane] = v;
    s += v; q += v * v;
  }
  ls[t] = s; lq[t] = q;
  __syncthreads();
  if (t < 64) {
    float S = ls[t] + ls[t + 64] + ls[t + 128] + ls[t + 192];
    float Q = lq[t] + lq[t + 64] + lq[t + 128] + lq[t + 192];
    atomicAdd(&sums[t], S);
    atomicAdd(&sumsq[t], Q);
  }
}

// ---------------- Set2Set: LSTM cell (1 block, 256 threads) ----------------
__global__ __launch_bounds__(256) void k_lstm(const float* __restrict__ Wih, const float* __restrict__ Whh,
                                              const float* __restrict__ bih, const float* __restrict__ bhh,
                                              float* __restrict__ sm) {
  __shared__ float qs[128], hsl[64], gates[256];
  int t = threadIdx.x;
  if (t < 128) qs[t] = sm[SM_QS + t];
  if (t < 64) hsl[t] = sm[SM_HS + t];
  __syncthreads();
  float g = bih[t] + bhh[t];
#pragma unroll 16
  for (int k = 0; k < 128; ++k) g += qs[k] * Wih[t * 128 + k];
#pragma unroll 16
  for (int k = 0; k < 64; ++k) g += hsl[k] * Whh[t * 64 + k];
  gates[t] = g;
  __syncthreads();
  if (t < 64) {
    float ig = 1.f / (1.f + expf(-gates[t]));
    float fg = 1.f / (1.f + expf(-gates[64 + t]));
    float gg = tanhf(gates[128 + t]);
    float og = 1.f / (1.f + expf(-gates[192 + t]));
    float c = fg * sm[SM_C + t] + ig * gg;
    float hsn = og * tanhf(c);
    sm[SM_C + t] = c;
    sm[SM_HS + t] = hsn;
  }
}

// ---------------- attention logits e[i] = gn3(h)[i] . hs, track max ----------------
__global__ __launch_bounds__(256) void k_e(const float* __restrict__ h, const float* __restrict__ sm,
                                           const float* __restrict__ gw, const float* __restrict__ gb,
                                           const float* __restrict__ gms,
                                           const float* __restrict__ sums, const float* __restrict__ sumsq,
                                           float* __restrict__ e, unsigned* __restrict__ maxe) {
  __shared__ float hv[64], tmp[64], eoffs;
  __shared__ float wmax[4];
  int t = threadIdx.x;
  if (t < 64) {
    float sc, sh;
    gn_affine(t, gw, gb, gms, sums, sumsq, sc, sh);
    float hs = sm[SM_HS + t];
    hv[t] = sc * hs;
    tmp[t] = sh * hs;
  }
  __syncthreads();
  if (t == 0) {
    float s = 0.f;
    for (int k = 0; k < 64; ++k) s += tmp[k];
    eoffs = s;
  }
  __syncthreads();
  int lane = t & 63, w = t >> 6;
  float hvl = hv[lane];
  float eoff = eoffs;
  float lmax = -3.4e38f;
  long nwaves = (long)gridDim.x * 4;
  for (long i = (long)blockIdx.x * 4 + w; i < NN; i += nwaves) {
    float v = h[i * 64 + lane] * hvl;
#pragma unroll
    for (int off = 32; off; off >>= 1) v += __shfl_xor(v, off, 64);
    float ei = v + eoff;
    if (lane == 0) e[i] = ei;
    lmax = fmaxf(lmax, ei);
  }
  if (lane == 0) wmax[w] = lmax;
  __syncthreads();
  if (t == 0) {
    float m = fmaxf(fmaxf(wmax[0], wmax[1]), fmaxf(wmax[2], wmax[3]));
    atomicMax(maxe, encf(m));
  }
}

// ---------------- softmax accumulate ----------------
__global__ __launch_bounds__(256) void k_soft(const float* __restrict__ h, const float* __restrict__ e,
                                              const unsigned* __restrict__ maxe,
                                              float* __restrict__ racc, float* __restrict__ Z) {
  __shared__ float lr[4][64];
  __shared__ float lz[4];
  int t = threadIdx.x, lane = t & 63, w = t >> 6;
  float mx = decf(*maxe);
  float r = 0.f, z = 0.f;
  long nwaves = (long)gridDim.x * 4;
  for (long i = (long)blockIdx.x * 4 + w; i < NN; i += nwaves) {
    float p = expf(e[i] - mx);
    r += p * h[i * 64 + lane];
    z += p;
  }
  lr[w][lane] = r;
  if (lane == 0) lz[w] = z;
  __syncthreads();
  if (t < 64) {
    float R = lr[0][t] + lr[1][t] + lr[2][t] + lr[3][t];
    atomicAdd(&racc[t], R);
  }
  if (t == 0) atomicAdd(Z, lz[0] + lz[1] + lz[2] + lz[3]);
}

// ---------------- q_star update (+ final output write) ----------------
__global__ __launch_bounds__(64) void k_qstar(const float* __restrict__ racc, const float* __restrict__ Z,
                                              const float* __restrict__ gw, const float* __restrict__ gb,
                                              const float* __restrict__ gms,
                                              const float* __restrict__ sums, const float* __restrict__ sumsq,
                                              float* __restrict__ sm, float* __restrict__ out) {
  int t = threadIdx.x;
  if (t < 64) {
    float sc, sh;
    gn_affine(t, gw, gb, gms, sums, sumsq, sc, sh);
    float r = sc * racc[t] / Z[0] + sh;
    float hs = sm[SM_HS + t];
    sm[SM_QS + t] = hs;
    sm[SM_QS + 64 + t] = r;
    if (out) { out[t] = hs; out[64 + t] = r; }
  }
}

extern "C" void kernel_launch(void* const* d_in, const int* in_sizes, int n_in,
                              void* d_out, int out_size, void* d_ws, size_t ws_size,
                              hipStream_t stream) {
  const float* x     = (const float*)d_in[0];
  const float* gn0_w = (const float*)d_in[1];
  const float* gn0_b = (const float*)d_in[2];
  const float* gn0_ms= (const float*)d_in[3];
  const float* W1    = (const float*)d_in[4];
  const float* b1    = (const float*)d_in[5];
  const float* a1    = (const float*)d_in[6];
  const float* gn1_w = (const float*)d_in[7];
  const float* gn1_b = (const float*)d_in[8];
  const float* gn1_ms= (const float*)d_in[9];
  const float* W2    = (const float*)d_in[10];
  const float* b2    = (const float*)d_in[11];
  const float* a2    = (const float*)d_in[12];
  const float* gn2_w = (const float*)d_in[13];
  const float* gn2_b = (const float*)d_in[14];
  const float* gn2_ms= (const float*)d_in[15];
  const float* W3    = (const float*)d_in[16];
  const float* b3    = (const float*)d_in[17];
  const float* gn3_w = (const float*)d_in[18];
  const float* gn3_b = (const float*)d_in[19];
  const float* gn3_ms= (const float*)d_in[20];
  const float* Wih   = (const float*)d_in[21];
  const float* Whh   = (const float*)d_in[22];
  const float* bih   = (const float*)d_in[23];
  const float* bhh   = (const float*)d_in[24];
  const int*   eidx  = (const int*)d_in[25];
  const int* esrc = eidx;
  const int* edst = eidx + NE;

  float* sm   = (float*)d_ws;
  float* dinv = sm + OFF_DINV;
  float* ebuf = sm + OFF_E;
  float* h    = sm + OFF_H;
  float* y    = sm + OFF_Y;
  int* degi   = (int*)(sm + OFF_INT);
  int* rowptr = degi + NPAD;          // NN+1
  int* cursor = rowptr + NPAD;
  int* col    = cursor + NPAD;        // NE
  int* bsum   = col + NE;             // NSCAN1
  float* out  = (float*)d_out;

  // zero small accumulators + degree histogram
  hipMemsetAsync(sm, 0, SM_COUNT * sizeof(float), stream);
  hipMemsetAsync(degi, 0, NN * sizeof(int), stream);

  // CSR build (once)
  k_deg<<<2048, 256, 0, stream>>>(edst, degi);
  k_scan1<<<NSCAN1, 256, 0, stream>>>(degi, rowptr, bsum);
  k_scan2<<<1, 512, 0, stream>>>(bsum);
  k_scan3<<<NSCAN1, 256, 0, stream>>>(rowptr, bsum, degi, cursor, dinv);
  k_fill<<<2048, 256, 0, stream>>>(esrc, edst, cursor, col);

  k_sums4<<<1024, 256, 0, stream>>>(x, sm + SM_SUMS(0), sm + SM_SUMSQ(0));

  // layer 1
  k_mm<4><<<2048, 256, 0, stream>>>(x, W1, gn0_w, gn0_b, gn0_ms,
                                    sm + SM_SUMS(0), sm + SM_SUMSQ(0), dinv, y);
  k_gather_fin<<<2048, 256, 0, stream>>>(y, rowptr, col, dinv, b1, a1, h,
                                         sm + SM_SUMS(1), sm + SM_SUMSQ(1));

  // layer 2
  k_mm<64><<<2048, 256, 0, stream>>>(h, W2, gn1_w, gn1_b, gn1_ms,
                                     sm + SM_SUMS(1), sm + SM_SUMSQ(1), dinv, y);
  k_gather_fin<<<2048, 256, 0, stream>>>(y, rowptr, col, dinv, b2, a2, h,
                                         sm + SM_SUMS(2), sm + SM_SUMSQ(2));

  // layer 3 (no prelu)
  k_mm<64><<<2048, 256, 0, stream>>>(h, W3, gn2_w, gn2_b, gn2_ms,
                                     sm + SM_SUMS(2), sm + SM_SUMSQ(2), dinv, y);
  k_gather_fin<<<2048, 256, 0, stream>>>(y, rowptr, col, dinv, b3, nullptr, h,
                                         sm + SM_SUMS(3), sm + SM_SUMSQ(3));

  // Set2Set, 3 steps
  for (int s = 0; s < 3; ++s) {
    k_lstm<<<1, 256, 0, stream>>>(Wih, Whh, bih, bhh, sm);
    k_e<<<1024, 256, 0, stream>>>(h, sm, gn3_w, gn3_b, gn3_ms,
                                  sm + SM_SUMS(3), sm + SM_SUMSQ(3),
                                  ebuf, (unsigned*)(sm + SM_MAXE(s)));
    k_soft<<<1024, 256, 0, stream>>>(h, ebuf, (const unsigned*)(sm + SM_MAXE(s)),
                                     sm + SM_RACC(s), sm + SM_Z(s));
    k_qstar<<<1, 64, 0, stream>>>(sm + SM_RACC(s), sm + SM_Z(s),
                                  gn3_w, gn3_b, gn3_ms,
                                  sm + SM_SUMS(3), sm + SM_SUMSQ(3),
                                  sm, (s == 2) ? out : nullptr);
  }
}